// Round 2
// baseline (322.127 us; speedup 1.0000x reference)
//
#include <hip/hip_runtime.h>
#include <cstddef>

// SSA forward, round 16 (2nd resubmit — rounds 17/18 bench infra failures):
//  - REVERT gemm8 to BK=128 (round-14 proven: 72 VGPR, 25% occupancy; BK=256
//    was neutral-negative — 4th confirmation of the m97-structure plateau law).
//  - finalize folded into apply kernels (each thread reduces its channel's 8
//    partials in the SAME fp order as finalize8_k -> bit-identical affine,
//    degenerate-BN var=0 exactness preserved). Dispatches 11 -> 9.

#define CC 512
#define BB 32
#define NN 1024

typedef __attribute__((ext_vector_type(4))) float v4f;
typedef __attribute__((ext_vector_type(2))) float v2f;
typedef __attribute__((ext_vector_type(4))) int v4i;
typedef __attribute__((ext_vector_type(8))) int v8i;
typedef unsigned char uchar;
typedef unsigned long long ull;

// ---- soft fallbacks --------------------------------------------------------------
__device__ __forceinline__ uchar f2e4s(float v) {
  const uchar s = (v < 0.f) ? 0x80 : 0x00;
  float a = fabsf(v);
  if (a >= 464.f) return s | 0x7E;
  if (a < 0.015625f) {
    int q = (int)rintf(a * 512.f);
    return s | (uchar)q;
  }
  const int e = (int)((__float_as_uint(a) >> 23) & 0xFF) - 126;
  const float scale = __uint_as_float((unsigned)(4 - e + 127) << 23);
  const int q = (int)rintf(a * scale);
  int code = ((e - 1 + 7) << 3) + (q - 8);
  if (code > 0x7E) code = 0x7E;
  return s | (uchar)code;
}
__device__ __forceinline__ float e42f(uchar b) {
  const int e = (b >> 3) & 15, m = b & 7;
  const float mag = e ? __uint_as_float((unsigned)((e + 120) << 23) | ((unsigned)m << 20))
                      : (float)m * 0.001953125f;
  return (b & 0x80) ? -mag : mag;
}

// ---- HW converters (gfx950 OCP e4m3), guarded ------------------------------------
__device__ __forceinline__ unsigned pk4_fp8(float a0, float a1, float a2, float a3) {
#if __has_builtin(__builtin_amdgcn_cvt_pk_fp8_f32)
  int r = __builtin_amdgcn_cvt_pk_fp8_f32(a0, a1, 0, false);
  r = __builtin_amdgcn_cvt_pk_fp8_f32(a2, a3, r, true);
  return (unsigned)r;
#else
  return (unsigned)f2e4s(a0) | ((unsigned)f2e4s(a1) << 8) |
         ((unsigned)f2e4s(a2) << 16) | ((unsigned)f2e4s(a3) << 24);
#endif
}
__device__ __forceinline__ uchar enc1(float v) {
#if __has_builtin(__builtin_amdgcn_cvt_pk_fp8_f32)
  return (uchar)(__builtin_amdgcn_cvt_pk_fp8_f32(v, v, 0, false) & 0xFF);
#else
  return f2e4s(v);
#endif
}
template <bool HI>
__device__ __forceinline__ v2f dec2(int src) {
#if __has_builtin(__builtin_amdgcn_cvt_pk_f32_fp8)
  return __builtin_amdgcn_cvt_pk_f32_fp8(src, HI);
#else
  v2f r;
  const int s = HI ? (src >> 16) : src;
  r[0] = e42f((uchar)s);
  r[1] = e42f((uchar)(s >> 8));
  return r;
#endif
}

__device__ __forceinline__ void gload16(const void* g, void* l) {
  __builtin_amdgcn_global_load_lds(
      (const __attribute__((address_space(1))) unsigned int*)g,
      (__attribute__((address_space(3))) unsigned int*)l, 16, 0, 0);
}

// ---- channel affine from 8 partials (same fp order as the old finalize) ----------
__device__ __forceinline__ float2 chan_affine(const float* __restrict__ P, int c,
                                              float g, float bt) {
  const float* pc = P + (size_t)c * 16;
  float S = 0.f, Q = 0.f;
#pragma unroll
  for (int t = 0; t < 8; t++) { S += pc[2 * t]; Q += pc[2 * t + 1]; }
  const float mean = S * (1.f / 32768.f);
  const float var = fmaxf(Q * (1.f / 32768.f) - mean * mean, 0.f);
  const float rinv = 1.f / sqrtf(var + 1e-5f);
  const float a = g * rinv;
  return make_float2(a, bt - mean * a);
}

// ---------------- batched NT GEMM, MX fp8, 128x128 tile, BK=128 ------------------
// (round-14 proven config.)  EPI: 0 = fp8 (kv ints); 1 = attn spike {0,0x38};
// 2 = fp8 pre-act; 3 = +bias[row] then fp8 pre-act.
template <int EPI>
__global__ __launch_bounds__(256) void gemm8(const uchar* __restrict__ A,
                                             const uchar* __restrict__ B,
                                             uchar* __restrict__ Cout,
                                             const float* __restrict__ bias,
                                             int M, int N, int K,
                                             long sA, long sB, long sC) {
  __shared__ __align__(16) uchar lds[32768];  // A [0,16384), B [16384,32768)
  const int b = blockIdx.z;
  const uchar* Ab = A + (size_t)b * sA;
  const uchar* Bb = B + (size_t)b * sB;
  const int m0 = blockIdx.y * 128, n0 = blockIdx.x * 128;
  const int tid = threadIdx.x;
  const int wave = tid >> 6, lane = tid & 63;
  const int lrow = lane & 15, lquad = lane >> 4;
  const int wr = wave >> 1, wc = wave & 1;

  v4f acc[4][4];
#pragma unroll
  for (int i = 0; i < 4; i++)
#pragma unroll
    for (int j = 0; j < 4; j++) acc[i][j] = (v4f)0.f;

  const uchar* gA0 = Ab + (size_t)(m0 + 32 * wave + lrow) * K + lquad * 32;
  const uchar* gA1 = gA0 + (size_t)16 * K;
  const uchar* gB0 = Bb + (size_t)(n0 + 32 * wave + lrow) * K + lquad * 32;
  const uchar* gB1 = gB0 + (size_t)16 * K;
  uchar* lA0 = lds + (2 * wave) * 2048;
  uchar* lA1 = lA0 + 2048;
  uchar* lB0 = lds + 16384 + (2 * wave) * 2048;
  uchar* lB1 = lB0 + 2048;

  for (int k0 = 0; k0 < K; k0 += 128) {
    gload16(gA0, lA0);
    gload16(gA0 + 16, lA0 + 1024);
    gload16(gA1, lA1);
    gload16(gA1 + 16, lA1 + 1024);
    gload16(gB0, lB0);
    gload16(gB0 + 16, lB0 + 1024);
    gload16(gB1, lB1);
    gload16(gB1 + 16, lB1 + 1024);
    gA0 += 128; gA1 += 128; gB0 += 128; gB1 += 128;
    __syncthreads();
    const uchar* ra = lds + (size_t)(4 * wr) * 2048 + 16 * lane;
    const uchar* rb = lds + 16384 + (size_t)(4 * wc) * 2048 + 16 * lane;
    v8i af[4], bf[4];
#pragma unroll
    for (int i = 0; i < 4; i++) {
      const v4i lo = *(const v4i*)(ra + i * 2048);
      const v4i hi = *(const v4i*)(ra + i * 2048 + 1024);
      af[i][0] = lo[0]; af[i][1] = lo[1]; af[i][2] = lo[2]; af[i][3] = lo[3];
      af[i][4] = hi[0]; af[i][5] = hi[1]; af[i][6] = hi[2]; af[i][7] = hi[3];
    }
#pragma unroll
    for (int j = 0; j < 4; j++) {
      const v4i lo = *(const v4i*)(rb + j * 2048);
      const v4i hi = *(const v4i*)(rb + j * 2048 + 1024);
      bf[j][0] = lo[0]; bf[j][1] = lo[1]; bf[j][2] = lo[2]; bf[j][3] = lo[3];
      bf[j][4] = hi[0]; bf[j][5] = hi[1]; bf[j][6] = hi[2]; bf[j][7] = hi[3];
    }
#pragma unroll
    for (int i = 0; i < 4; i++)
#pragma unroll
      for (int j = 0; j < 4; j++)
        acc[i][j] = __builtin_amdgcn_mfma_scale_f32_16x16x128_f8f6f4(
            af[i], bf[j], acc[i][j], 0, 0, 0, 127, 0, 127);
    __syncthreads();
  }

  if (EPI == 3) {
#pragma unroll
    for (int mi = 0; mi < 4; mi++)
#pragma unroll
      for (int r = 0; r < 4; r++) {
        const float bi = bias[m0 + 64 * wr + 16 * mi + lquad * 4 + r];
#pragma unroll
        for (int ni = 0; ni < 4; ni++) acc[mi][ni][r] += bi;
      }
  }

  // Epilogue. C/D layout: col = lane&15, row = lquad*4 + reg.
#pragma unroll
  for (int mi = 0; mi < 4; mi++) {
    const int row0 = m0 + 64 * wr + 16 * mi + lquad * 4;
#pragma unroll
    for (int ni = 0; ni < 4; ni++) {
      const int col = n0 + 64 * wc + 16 * ni + lrow;
      uchar* cp = Cout + (size_t)b * sC + (size_t)row0 * N + col;
      if (EPI == 1) {
#pragma unroll
        for (int r = 0; r < 4; r++) {
          const float u = (acc[mi][ni][r] * 0.125f) / 1.1f - 0.5f;
          cp[(size_t)r * N] = (u >= 0.f) ? (uchar)0x38 : (uchar)0;
        }
      } else {
        const unsigned pk = pk4_fp8(acc[mi][ni][0], acc[mi][ni][1],
                                    acc[mi][ni][2], acc[mi][ni][3]);
#pragma unroll
        for (int r = 0; r < 4; r++) cp[(size_t)r * N] = (uchar)(pk >> (8 * r));
      }
    }
  }
}

// -------- BN partial stats from stored fp8: grid (8, nch) -------------------------
__global__ __launch_bounds__(256) void stats_part8_k(const uchar* __restrict__ in,
                                                     float* __restrict__ P,
                                                     long bstride) {
  const int part = blockIdx.x, c = blockIdx.y;
  const int tid = threadIdx.x;
  const int bi = part * 4 + (tid >> 6);
  const int lane = tid & 63;
  const uchar* p = in + (size_t)bi * bstride + (size_t)c * 1024 + lane * 16;
  const uint4 u = *(const uint4*)p;
  const int w4[4] = {(int)u.x, (int)u.y, (int)u.z, (int)u.w};
  float s = 0.f, s2 = 0.f;
#pragma unroll
  for (int t = 0; t < 4; t++) {
    const v2f a = dec2<false>(w4[t]);
    const v2f bb = dec2<true>(w4[t]);
    s += (a[0] + a[1]) + (bb[0] + bb[1]);
    s2 += a[0] * a[0] + a[1] * a[1] + bb[0] * bb[0] + bb[1] * bb[1];
  }
#pragma unroll
  for (int off = 32; off > 0; off >>= 1) {
    s += __shfl_down(s, off, 64);
    s2 += __shfl_down(s2, off, 64);
  }
  __shared__ float rs[4], rq[4];
  const int w = tid >> 6;
  if (lane == 0) { rs[w] = s; rq[w] = s2; }
  __syncthreads();
  if (tid == 0) {
    float2 o = make_float2(rs[0] + rs[1] + rs[2] + rs[3],
                           rq[0] + rq[1] + rq[2] + rq[3]);
    *(float2*)(P + (size_t)(c * 8 + part) * 2) = o;
  }
}

// -------- fused BN(finalize)+apply+spike: q (transpose) and k/v, one dispatch -----
// blocks [0,16384): qT tiles; [16384,32768): k/v linear (8192 each).
__global__ __launch_bounds__(256) void apply_all_k(const uchar* __restrict__ qkv8,
                                                   uchar* __restrict__ q8,
                                                   uchar* __restrict__ k8,
                                                   uchar* __restrict__ v8,
                                                   const float* __restrict__ P,
                                                   const float* __restrict__ qg, const float* __restrict__ qb,
                                                   const float* __restrict__ kg, const float* __restrict__ kb,
                                                   const float* __restrict__ vg, const float* __restrict__ vb) {
  const int bid = blockIdx.x;
  const int tid = threadIdx.x;
  if (bid < 16384) {
    // q: BN-apply + spike + transpose -> q8 [B,N,C]
    __shared__ uchar tile[32][33];
    const int nb = bid & 31, cb = (bid >> 5) & 15, b = bid >> 9;
    const int n0 = nb * 32, c0 = cb * 32;
    const uchar* in = qkv8 + (size_t)b * (1536 * 1024);
    const int cl = tid >> 3;            // 0..31
    const int n4 = (tid & 7) * 4;       // 0..28
    const int c = c0 + cl;
    const float2 ab = chan_affine(P, c, qg[c], qb[c]);
    const unsigned w = *(const unsigned*)(in + (size_t)c * 1024 + n0 + n4);
    const v2f a = dec2<false>((int)w);
    const v2f bb = dec2<true>((int)w);
    tile[cl][n4 + 0] = (ab.x * a[0] + ab.y >= 1.1f) ? (uchar)0x38 : (uchar)0;
    tile[cl][n4 + 1] = (ab.x * a[1] + ab.y >= 1.1f) ? (uchar)0x38 : (uchar)0;
    tile[cl][n4 + 2] = (ab.x * bb[0] + ab.y >= 1.1f) ? (uchar)0x38 : (uchar)0;
    tile[cl][n4 + 3] = (ab.x * bb[1] + ab.y >= 1.1f) ? (uchar)0x38 : (uchar)0;
    __syncthreads();
    uchar* out = q8 + (size_t)b * (NN * CC);
    const int nl = tid >> 3;
    const int cq = (tid & 7) * 4;
    uchar4 v;
    v.x = tile[cq][nl]; v.y = tile[cq + 1][nl];
    v.z = tile[cq + 2][nl]; v.w = tile[cq + 3][nl];
    *(uchar4*)(out + (size_t)(n0 + nl) * CC + c0 + cq) = v;
  } else {
    // k/v: BN-apply + spike in [B,C,N]
    const int t0 = bid - 16384;
    const int sec = t0 >> 13;           // 0:k, 1:v
    const int blk = t0 & 8191;
    const size_t t = (size_t)blk * 256 + tid;
    const size_t i = t * 8;
    const int b = (int)(i >> 19);
    const int rem = (int)(i & 524287);
    const int c = rem >> 10, n = rem & 1023;
    const int cg = 512 + 512 * sec + c;
    const float2 ab = chan_affine(P, cg, sec ? vg[c] : kg[c], sec ? vb[c] : kb[c]);
    const uchar* src = qkv8 + (size_t)b * (1536 * 1024) + (size_t)cg * 1024 + n;
    const uint2 u = *(const uint2*)src;
    ull packed = 0;
    {
      const v2f a = dec2<false>((int)u.x);
      const v2f bb = dec2<true>((int)u.x);
      const float f[4] = {a[0], a[1], bb[0], bb[1]};
#pragma unroll
      for (int j = 0; j < 4; j++)
        packed |= ((ab.x * f[j] + ab.y >= 1.1f) ? 0x38ull : 0ull) << (8 * j);
    }
    {
      const v2f a = dec2<false>((int)u.y);
      const v2f bb = dec2<true>((int)u.y);
      const float f[4] = {a[0], a[1], bb[0], bb[1]};
#pragma unroll
      for (int j = 0; j < 4; j++)
        packed |= ((ab.x * f[j] + ab.y >= 1.1f) ? 0x38ull : 0ull) << (8 * (4 + j));
    }
    uchar* dst = (sec ? v8 : k8) + (size_t)b * (CC * NN) + (size_t)c * 1024 + n;
    *(ull*)dst = packed;
  }
}

// -------- final BN(finalize)+apply+spike -> fp32 output ---------------------------
__global__ __launch_bounds__(256) void apply_final_k(const uchar* __restrict__ in,
                                                     float* __restrict__ outp,
                                                     const float* __restrict__ Pp,
                                                     const float* __restrict__ pg,
                                                     const float* __restrict__ pb) {
  const size_t idx = ((size_t)blockIdx.x * 256 + threadIdx.x) * 8;
  const int c = (int)((idx >> 10) & (CC - 1));
  const float2 ab = chan_affine(Pp, c, pg[c], pb[c]);
  const uint2 u = *(const uint2*)(in + idx);
  float of[8];
  {
    const v2f a = dec2<false>((int)u.x);
    const v2f bb = dec2<true>((int)u.x);
    of[0] = (ab.x * a[0] + ab.y >= 1.1f) ? 1.f : 0.f;
    of[1] = (ab.x * a[1] + ab.y >= 1.1f) ? 1.f : 0.f;
    of[2] = (ab.x * bb[0] + ab.y >= 1.1f) ? 1.f : 0.f;
    of[3] = (ab.x * bb[1] + ab.y >= 1.1f) ? 1.f : 0.f;
  }
  {
    const v2f a = dec2<false>((int)u.y);
    const v2f bb = dec2<true>((int)u.y);
    of[4] = (ab.x * a[0] + ab.y >= 1.1f) ? 1.f : 0.f;
    of[5] = (ab.x * a[1] + ab.y >= 1.1f) ? 1.f : 0.f;
    of[6] = (ab.x * bb[0] + ab.y >= 1.1f) ? 1.f : 0.f;
    of[7] = (ab.x * bb[1] + ab.y >= 1.1f) ? 1.f : 0.f;
  }
  float* op = outp + idx;
  *(float4*)op = make_float4(of[0], of[1], of[2], of[3]);
  *(float4*)(op + 4) = make_float4(of[4], of[5], of[6], of[7]);
}

// -------- fused prep: x transpose->fp8 [blocks 0,16384) + weight cvt [16384,17408)
__global__ __launch_bounds__(256) void prep_k(const float* __restrict__ x,
                                              const float* __restrict__ w0, const float* __restrict__ w1,
                                              const float* __restrict__ w2, const float* __restrict__ w3,
                                              uchar* __restrict__ xT8,
                                              uchar* __restrict__ o0, uchar* __restrict__ o1,
                                              uchar* __restrict__ o2, uchar* __restrict__ o3) {
  const int bid = blockIdx.x;
  const int tid = threadIdx.x;
  if (bid < 16384) {
    __shared__ uchar tile[32][33];
    const int nb = bid & 31, cb = (bid >> 5) & 15, b = bid >> 9;
    const int n0 = nb * 32, c0 = cb * 32;
    const float* in = x + (size_t)b * (CC * NN);
    const int tx = tid & 31, ty = tid >> 5;
#pragma unroll
    for (int i = 0; i < 32; i += 8) {
      tile[ty + i][tx] = enc1(in[(size_t)(c0 + ty + i) * NN + n0 + tx]);
    }
    __syncthreads();
    uchar* o = xT8 + (size_t)b * (NN * CC);
    const int nl = tid >> 3;
    const int cq = (tid & 7) * 4;
    uchar4 v;
    v.x = tile[cq][nl]; v.y = tile[cq + 1][nl];
    v.z = tile[cq + 2][nl]; v.w = tile[cq + 3][nl];
    *(uchar4*)(o + (size_t)(n0 + nl) * CC + c0 + cq) = v;
  } else {
    const int t = bid - 16384;      // [0,1024)
    const int mat = t >> 8, blk = t & 255;
    const float* src = (mat == 0) ? w0 : (mat == 1) ? w1 : (mat == 2) ? w2 : w3;
    uchar* dst = (mat == 0) ? o0 : (mat == 1) ? o1 : (mat == 2) ? o2 : o3;
    const int i = (blk * 256 + tid) * 4;
    float4 v = *(const float4*)(src + i);
    *(unsigned*)(dst + i) = pk4_fp8(v.x, v.y, v.z, v.w);
  }
}

extern "C" void kernel_launch(void* const* d_in, const int* in_sizes, int n_in,
                              void* d_out, int out_size, void* d_ws, size_t ws_size,
                              hipStream_t stream) {
  const float* x          = (const float*)d_in[0];
  const float* q_w        = (const float*)d_in[1];
  const float* q_gamma    = (const float*)d_in[2];
  const float* q_beta     = (const float*)d_in[3];
  const float* k_w        = (const float*)d_in[4];
  const float* k_gamma    = (const float*)d_in[5];
  const float* k_beta     = (const float*)d_in[6];
  const float* v_w        = (const float*)d_in[7];
  const float* v_gamma    = (const float*)d_in[8];
  const float* v_beta     = (const float*)d_in[9];
  const float* proj_w     = (const float*)d_in[10];
  const float* proj_gamma = (const float*)d_in[11];
  const float* proj_beta  = (const float*)d_in[12];
  const float* proj_b     = (const float*)d_in[13];

  char* base = (char*)d_ws;
  const size_t MB = 1u << 20;
  uchar*  xT8    = (uchar*)base;                // 16 MB [B,N,C] fp8
  uchar*  qkv8   = (uchar*)(base + 16 * MB);    // 48 MB [B,1536,1024] fp8 pre-acts
  uchar*  q8     = (uchar*)(base + 64 * MB);    // 16 MB [B,N,C] fp8 spikes
  uchar*  k8     = (uchar*)(base + 80 * MB);    // 16 MB [B,C,N]
  uchar*  v8     = (uchar*)(base + 96 * MB);    // 16 MB [B,C,N]
  uchar*  kvT8   = (uchar*)(base + 112 * MB);   //  8 MB [B,d,c]
  uchar*  attnT8 = (uchar*)(base + 120 * MB);   // 16 MB [B,N,d]
  uchar*  outpre8= (uchar*)(base + 136 * MB);   // 16 MB [B,C,N] fp8 proj pre-acts
  uchar*  wqkv8  = (uchar*)(base + 152 * MB);   // stacked q|k|v fp8
  uchar*  wp8    = wqkv8 + 3 * CC * CC;
  float*  P      = (float*)(base + 154 * MB);   // conv partials [1536][8][2]
  float*  Pp     = P + 1536 * 16;               // proj partials [512][8][2]
  float* dout = (float*)d_out;

  const long QKVL = (long)3 * CC * NN;   // fp8 bytes per batch
  const long NCL  = (long)NN * CC;
  const long CNL  = (long)CC * NN;
  const long KVL  = (long)CC * CC;

  // fused prep: x -> xT8 fp8 + weights -> fp8
  prep_k<<<17408, 256, 0, stream>>>(x, q_w, k_w, v_w, proj_w, xT8,
                                    wqkv8, wqkv8 + CC * CC, wqkv8 + 2 * CC * CC, wp8);

  // merged q/k/v conv -> fp8 pre-acts
  gemm8<2><<<dim3(NN / 128, 1536 / 128, BB), 256, 0, stream>>>(
      wqkv8, xT8, qkv8, nullptr, 1536, NN, CC, 0, NCL, QKVL);

  // BN stats from stored fp8
  stats_part8_k<<<dim3(8, 1536), 256, 0, stream>>>(qkv8, P, QKVL);

  // fused finalize+apply: q (transpose) + k + v spikes, one dispatch
  apply_all_k<<<32768, 256, 0, stream>>>(qkv8, q8, k8, v8, P,
                                         q_gamma, q_beta, k_gamma, k_beta,
                                         v_gamma, v_beta);

  // kvT8[d][c] = sum_n v[d][n] k[c][n]
  gemm8<0><<<dim3(CC / 128, CC / 128, BB), 256, 0, stream>>>(
      v8, k8, kvT8, nullptr, CC, CC, NN, CNL, CNL, KVL);
  // attnT8[n][d] = spike( sum_c q8[n][c]*kvT8[d][c] * 0.125, vth=0.5 )
  gemm8<1><<<dim3(CC / 128, NN / 128, BB), 256, 0, stream>>>(
      q8, kvT8, attnT8, nullptr, NN, CC, CC, NCL, KVL, NCL);
  // proj -> fp8 pre-acts (+bias)
  gemm8<3><<<dim3(NN / 128, CC / 128, BB), 256, 0, stream>>>(
      wp8, attnT8, outpre8, proj_b, CC, NN, CC, 0, NCL, CNL);

  // final BN stats + fused finalize+apply -> fp32 out
  stats_part8_k<<<dim3(8, CC), 256, 0, stream>>>(outpre8, Pp, CNL);
  apply_final_k<<<8192, 256, 0, stream>>>(outpre8, dout, Pp, proj_gamma, proj_beta);
}

// Round 3
// 313.125 us; speedup vs baseline: 1.0287x; 1.0287x over previous
//
#include <hip/hip_runtime.h>
#include <cstddef>

// SSA forward, round 19:
//  - NEW gemm8p: 256x256 tile, BK=128, 8 waves (2Mx4N), double-buffered 128KB LDS,
//    4-phase-per-K-tile schedule (per-phase s_barrier + lgkmcnt(0) + setprio MFMA
//    cluster; staging for K-tile t+1 issued in phases 0/1 of tile t; single
//    vmcnt(0) checkpoint at end of phase 3 — loads get ~3 phases of latency cover).
//    This is the guide's T3+T4(+T5) counted-vmcnt escape from the m97 plateau
//    (MfmaUtil was 15%, 800 TF = 17% of MX-fp8 ceiling, nothing saturated).
//    Accumulation order per acc element unchanged (ascending K-tiles) -> outputs
//    bit-identical -> absmax 0.0 preserved.
//  - Used for gemm<2> (1536x1024), gemm<1> (1024x512), gemm<3> (512x1024).
//    gemm<0> (512x512 -> only 128 blocks at 256^2) stays on proven 128^2 gemm8.

#define CC 512
#define BB 32
#define NN 1024

typedef __attribute__((ext_vector_type(4))) float v4f;
typedef __attribute__((ext_vector_type(2))) float v2f;
typedef __attribute__((ext_vector_type(4))) int v4i;
typedef __attribute__((ext_vector_type(8))) int v8i;
typedef unsigned char uchar;
typedef unsigned long long ull;

// ---- soft fallbacks --------------------------------------------------------------
__device__ __forceinline__ uchar f2e4s(float v) {
  const uchar s = (v < 0.f) ? 0x80 : 0x00;
  float a = fabsf(v);
  if (a >= 464.f) return s | 0x7E;
  if (a < 0.015625f) {
    int q = (int)rintf(a * 512.f);
    return s | (uchar)q;
  }
  const int e = (int)((__float_as_uint(a) >> 23) & 0xFF) - 126;
  const float scale = __uint_as_float((unsigned)(4 - e + 127) << 23);
  const int q = (int)rintf(a * scale);
  int code = ((e - 1 + 7) << 3) + (q - 8);
  if (code > 0x7E) code = 0x7E;
  return s | (uchar)code;
}
__device__ __forceinline__ float e42f(uchar b) {
  const int e = (b >> 3) & 15, m = b & 7;
  const float mag = e ? __uint_as_float((unsigned)((e + 120) << 23) | ((unsigned)m << 20))
                      : (float)m * 0.001953125f;
  return (b & 0x80) ? -mag : mag;
}

// ---- HW converters (gfx950 OCP e4m3), guarded ------------------------------------
__device__ __forceinline__ unsigned pk4_fp8(float a0, float a1, float a2, float a3) {
#if __has_builtin(__builtin_amdgcn_cvt_pk_fp8_f32)
  int r = __builtin_amdgcn_cvt_pk_fp8_f32(a0, a1, 0, false);
  r = __builtin_amdgcn_cvt_pk_fp8_f32(a2, a3, r, true);
  return (unsigned)r;
#else
  return (unsigned)f2e4s(a0) | ((unsigned)f2e4s(a1) << 8) |
         ((unsigned)f2e4s(a2) << 16) | ((unsigned)f2e4s(a3) << 24);
#endif
}
__device__ __forceinline__ uchar enc1(float v) {
#if __has_builtin(__builtin_amdgcn_cvt_pk_fp8_f32)
  return (uchar)(__builtin_amdgcn_cvt_pk_fp8_f32(v, v, 0, false) & 0xFF);
#else
  return f2e4s(v);
#endif
}
template <bool HI>
__device__ __forceinline__ v2f dec2(int src) {
#if __has_builtin(__builtin_amdgcn_cvt_pk_f32_fp8)
  return __builtin_amdgcn_cvt_pk_f32_fp8(src, HI);
#else
  v2f r;
  const int s = HI ? (src >> 16) : src;
  r[0] = e42f((uchar)s);
  r[1] = e42f((uchar)(s >> 8));
  return r;
#endif
}

__device__ __forceinline__ void gload16(const void* g, void* l) {
  __builtin_amdgcn_global_load_lds(
      (const __attribute__((address_space(1))) unsigned int*)g,
      (__attribute__((address_space(3))) unsigned int*)l, 16, 0, 0);
}

// ---- channel affine from 8 partials (same fp order as the old finalize) ----------
__device__ __forceinline__ float2 chan_affine(const float* __restrict__ P, int c,
                                              float g, float bt) {
  const float* pc = P + (size_t)c * 16;
  float S = 0.f, Q = 0.f;
#pragma unroll
  for (int t = 0; t < 8; t++) { S += pc[2 * t]; Q += pc[2 * t + 1]; }
  const float mean = S * (1.f / 32768.f);
  const float var = fmaxf(Q * (1.f / 32768.f) - mean * mean, 0.f);
  const float rinv = 1.f / sqrtf(var + 1e-5f);
  const float a = g * rinv;
  return make_float2(a, bt - mean * a);
}

// ---------------- batched NT GEMM, MX fp8, 128x128 tile, BK=128 (legacy path) -----
// EPI: 0 = fp8 (kv ints); 1 = attn spike {0,0x38}; 2 = fp8 pre-act; 3 = +bias.
template <int EPI>
__global__ __launch_bounds__(256) void gemm8(const uchar* __restrict__ A,
                                             const uchar* __restrict__ B,
                                             uchar* __restrict__ Cout,
                                             const float* __restrict__ bias,
                                             int M, int N, int K,
                                             long sA, long sB, long sC) {
  __shared__ __align__(16) uchar lds[32768];  // A [0,16384), B [16384,32768)
  const int b = blockIdx.z;
  const uchar* Ab = A + (size_t)b * sA;
  const uchar* Bb = B + (size_t)b * sB;
  const int m0 = blockIdx.y * 128, n0 = blockIdx.x * 128;
  const int tid = threadIdx.x;
  const int wave = tid >> 6, lane = tid & 63;
  const int lrow = lane & 15, lquad = lane >> 4;
  const int wr = wave >> 1, wc = wave & 1;

  v4f acc[4][4];
#pragma unroll
  for (int i = 0; i < 4; i++)
#pragma unroll
    for (int j = 0; j < 4; j++) acc[i][j] = (v4f)0.f;

  const uchar* gA0 = Ab + (size_t)(m0 + 32 * wave + lrow) * K + lquad * 32;
  const uchar* gA1 = gA0 + (size_t)16 * K;
  const uchar* gB0 = Bb + (size_t)(n0 + 32 * wave + lrow) * K + lquad * 32;
  const uchar* gB1 = gB0 + (size_t)16 * K;
  uchar* lA0 = lds + (2 * wave) * 2048;
  uchar* lA1 = lA0 + 2048;
  uchar* lB0 = lds + 16384 + (2 * wave) * 2048;
  uchar* lB1 = lB0 + 2048;

  for (int k0 = 0; k0 < K; k0 += 128) {
    gload16(gA0, lA0);
    gload16(gA0 + 16, lA0 + 1024);
    gload16(gA1, lA1);
    gload16(gA1 + 16, lA1 + 1024);
    gload16(gB0, lB0);
    gload16(gB0 + 16, lB0 + 1024);
    gload16(gB1, lB1);
    gload16(gB1 + 16, lB1 + 1024);
    gA0 += 128; gA1 += 128; gB0 += 128; gB1 += 128;
    __syncthreads();
    const uchar* ra = lds + (size_t)(4 * wr) * 2048 + 16 * lane;
    const uchar* rb = lds + 16384 + (size_t)(4 * wc) * 2048 + 16 * lane;
    v8i af[4], bf[4];
#pragma unroll
    for (int i = 0; i < 4; i++) {
      const v4i lo = *(const v4i*)(ra + i * 2048);
      const v4i hi = *(const v4i*)(ra + i * 2048 + 1024);
      af[i][0] = lo[0]; af[i][1] = lo[1]; af[i][2] = lo[2]; af[i][3] = lo[3];
      af[i][4] = hi[0]; af[i][5] = hi[1]; af[i][6] = hi[2]; af[i][7] = hi[3];
    }
#pragma unroll
    for (int j = 0; j < 4; j++) {
      const v4i lo = *(const v4i*)(rb + j * 2048);
      const v4i hi = *(const v4i*)(rb + j * 2048 + 1024);
      bf[j][0] = lo[0]; bf[j][1] = lo[1]; bf[j][2] = lo[2]; bf[j][3] = lo[3];
      bf[j][4] = hi[0]; bf[j][5] = hi[1]; bf[j][6] = hi[2]; bf[j][7] = hi[3];
    }
#pragma unroll
    for (int i = 0; i < 4; i++)
#pragma unroll
      for (int j = 0; j < 4; j++)
        acc[i][j] = __builtin_amdgcn_mfma_scale_f32_16x16x128_f8f6f4(
            af[i], bf[j], acc[i][j], 0, 0, 0, 127, 0, 127);
    __syncthreads();
  }

  if (EPI == 3) {
#pragma unroll
    for (int mi = 0; mi < 4; mi++)
#pragma unroll
      for (int r = 0; r < 4; r++) {
        const float bi = bias[m0 + 64 * wr + 16 * mi + lquad * 4 + r];
#pragma unroll
        for (int ni = 0; ni < 4; ni++) acc[mi][ni][r] += bi;
      }
  }

  // Epilogue. C/D layout: col = lane&15, row = lquad*4 + reg.
#pragma unroll
  for (int mi = 0; mi < 4; mi++) {
    const int row0 = m0 + 64 * wr + 16 * mi + lquad * 4;
#pragma unroll
    for (int ni = 0; ni < 4; ni++) {
      const int col = n0 + 64 * wc + 16 * ni + lrow;
      uchar* cp = Cout + (size_t)b * sC + (size_t)row0 * N + col;
      if (EPI == 1) {
#pragma unroll
        for (int r = 0; r < 4; r++) {
          const float u = (acc[mi][ni][r] * 0.125f) / 1.1f - 0.5f;
          cp[(size_t)r * N] = (u >= 0.f) ? (uchar)0x38 : (uchar)0;
        }
      } else {
        const unsigned pk = pk4_fp8(acc[mi][ni][0], acc[mi][ni][1],
                                    acc[mi][ni][2], acc[mi][ni][3]);
#pragma unroll
        for (int r = 0; r < 4; r++) cp[(size_t)r * N] = (uchar)(pk >> (8 * r));
      }
    }
  }
}

// ---------------- phased batched NT GEMM, MX fp8, 256x256 tile, BK=128 ------------
// 8 waves (2M x 4N). LDS: 2 buffers x (A 32KB | B 32KB) = 128KB, double-buffered.
// Per K-tile: 4 phases of {ds_read A-pair (+B all, phase 0) ; staging issue
// (phases 0/1) ; barrier ; lgkmcnt(0) ; setprio(1) 8xMFMA setprio(0) ; barrier},
// with one vmcnt(0) checkpoint at the end of phase 3 (loads issued ~3 phases
// earlier -> latency hidden under MFMA; never drains mid-pipeline).
template <int EPI>
__global__ __launch_bounds__(512, 2) void gemm8p(const uchar* __restrict__ A,
                                                 const uchar* __restrict__ B,
                                                 uchar* __restrict__ Cout,
                                                 const float* __restrict__ bias,
                                                 int M, int N, int K,
                                                 long sA, long sB, long sC) {
  __shared__ __align__(16) uchar lds[131072];
  const int b = blockIdx.z;
  const uchar* Ab = A + (size_t)b * sA;
  const uchar* Bb = B + (size_t)b * sB;
  const int m0 = blockIdx.y * 256, n0 = blockIdx.x * 256;
  const int tid = threadIdx.x;
  const int wave = tid >> 6, lane = tid & 63;
  const int lrow = lane & 15, lquad = lane >> 4;
  const int wr = wave >> 2, wc = wave & 3;

  v4f acc[8][4];
#pragma unroll
  for (int i = 0; i < 8; i++)
#pragma unroll
    for (int j = 0; j < 4; j++) acc[i][j] = (v4f)0.f;

  // staging: wave w covers A rows m0+32w..+31 and B rows n0+32w..+31 (groups 2w,2w+1)
  const uchar* gA0 = Ab + (size_t)(m0 + 32 * wave + lrow) * K + lquad * 32;
  const uchar* gA1 = gA0 + (size_t)16 * K;
  const uchar* gB0 = Bb + (size_t)(n0 + 32 * wave + lrow) * K + lquad * 32;
  const uchar* gB1 = gB0 + (size_t)16 * K;

  const int NT = K >> 7;

#define SSA_STAGE_A(bufi)                                   \
  do {                                                      \
    uchar* la = lds + (bufi) * 65536 + (2 * wave) * 2048;   \
    gload16(gA0, la);                                       \
    gload16(gA0 + 16, la + 1024);                           \
    gload16(gA1, la + 2048);                                \
    gload16(gA1 + 16, la + 3072);                           \
  } while (0)
#define SSA_STAGE_B(bufi)                                   \
  do {                                                      \
    uchar* lb = lds + (bufi) * 65536 + 32768 + (2 * wave) * 2048; \
    gload16(gB0, lb);                                       \
    gload16(gB0 + 16, lb + 1024);                           \
    gload16(gB1, lb + 2048);                                \
    gload16(gB1 + 16, lb + 3072);                           \
  } while (0)

  // prologue: stage K-tile 0 into buffer 0
  SSA_STAGE_A(0);
  SSA_STAGE_B(0);
  gA0 += 128; gA1 += 128; gB0 += 128; gB1 += 128;
  asm volatile("s_waitcnt vmcnt(0)" ::: "memory");
  __builtin_amdgcn_s_barrier();

  for (int kt = 0; kt < NT; ++kt) {
    const int cur = kt & 1;
    const int nxt = cur ^ 1;
    const bool more = (kt + 1 < NT);
    const uchar* raA = lds + cur * 65536 + (8 * wr) * 2048 + 16 * lane;
    const uchar* raB = lds + cur * 65536 + 32768 + (4 * wc) * 2048 + 16 * lane;
    v8i bf[4];
#pragma unroll
    for (int p = 0; p < 4; ++p) {
      // ds-load this phase's A fragment pair (mi = 2p, 2p+1)
      const uchar* ra = raA + (2 * p) * 2048;
      const v4i a0lo = *(const v4i*)(ra);
      const v4i a0hi = *(const v4i*)(ra + 1024);
      const v4i a1lo = *(const v4i*)(ra + 2048);
      const v4i a1hi = *(const v4i*)(ra + 3072);
      if (p == 0) {
#pragma unroll
        for (int j = 0; j < 4; ++j) {
          const v4i lo = *(const v4i*)(raB + j * 2048);
          const v4i hi = *(const v4i*)(raB + j * 2048 + 1024);
          bf[j][0] = lo[0]; bf[j][1] = lo[1]; bf[j][2] = lo[2]; bf[j][3] = lo[3];
          bf[j][4] = hi[0]; bf[j][5] = hi[1]; bf[j][6] = hi[2]; bf[j][7] = hi[3];
        }
        if (more) SSA_STAGE_A(nxt);
      }
      if (p == 1 && more) {
        SSA_STAGE_B(nxt);
        gA0 += 128; gA1 += 128; gB0 += 128; gB1 += 128;
      }
      __builtin_amdgcn_s_barrier();
      asm volatile("s_waitcnt lgkmcnt(0)" ::: "memory");
      __builtin_amdgcn_sched_barrier(0);
      __builtin_amdgcn_s_setprio(1);
      v8i af0, af1;
      af0[0] = a0lo[0]; af0[1] = a0lo[1]; af0[2] = a0lo[2]; af0[3] = a0lo[3];
      af0[4] = a0hi[0]; af0[5] = a0hi[1]; af0[6] = a0hi[2]; af0[7] = a0hi[3];
      af1[0] = a1lo[0]; af1[1] = a1lo[1]; af1[2] = a1lo[2]; af1[3] = a1lo[3];
      af1[4] = a1hi[0]; af1[5] = a1hi[1]; af1[6] = a1hi[2]; af1[7] = a1hi[3];
#pragma unroll
      for (int j = 0; j < 4; ++j) {
        acc[2 * p][j] = __builtin_amdgcn_mfma_scale_f32_16x16x128_f8f6f4(
            af0, bf[j], acc[2 * p][j], 0, 0, 0, 127, 0, 127);
        acc[2 * p + 1][j] = __builtin_amdgcn_mfma_scale_f32_16x16x128_f8f6f4(
            af1, bf[j], acc[2 * p + 1][j], 0, 0, 0, 127, 0, 127);
      }
      __builtin_amdgcn_s_setprio(0);
      if (p == 3 && more) asm volatile("s_waitcnt vmcnt(0)" ::: "memory");
      __builtin_amdgcn_s_barrier();
    }
  }
#undef SSA_STAGE_A
#undef SSA_STAGE_B

  if (EPI == 3) {
#pragma unroll
    for (int mi = 0; mi < 8; mi++)
#pragma unroll
      for (int r = 0; r < 4; r++) {
        const float bi = bias[m0 + 128 * wr + 16 * mi + lquad * 4 + r];
#pragma unroll
        for (int ni = 0; ni < 4; ni++) acc[mi][ni][r] += bi;
      }
  }

  // Epilogue. C/D layout: col = lane&15, row = lquad*4 + reg.
#pragma unroll
  for (int mi = 0; mi < 8; mi++) {
    const int row0 = m0 + 128 * wr + 16 * mi + lquad * 4;
#pragma unroll
    for (int ni = 0; ni < 4; ni++) {
      const int col = n0 + 64 * wc + 16 * ni + lrow;
      uchar* cp = Cout + (size_t)b * sC + (size_t)row0 * N + col;
      if (EPI == 1) {
#pragma unroll
        for (int r = 0; r < 4; r++) {
          const float u = (acc[mi][ni][r] * 0.125f) / 1.1f - 0.5f;
          cp[(size_t)r * N] = (u >= 0.f) ? (uchar)0x38 : (uchar)0;
        }
      } else {
        const unsigned pk = pk4_fp8(acc[mi][ni][0], acc[mi][ni][1],
                                    acc[mi][ni][2], acc[mi][ni][3]);
#pragma unroll
        for (int r = 0; r < 4; r++) cp[(size_t)r * N] = (uchar)(pk >> (8 * r));
      }
    }
  }
}

// -------- BN partial stats from stored fp8: grid (8, nch) -------------------------
__global__ __launch_bounds__(256) void stats_part8_k(const uchar* __restrict__ in,
                                                     float* __restrict__ P,
                                                     long bstride) {
  const int part = blockIdx.x, c = blockIdx.y;
  const int tid = threadIdx.x;
  const int bi = part * 4 + (tid >> 6);
  const int lane = tid & 63;
  const uchar* p = in + (size_t)bi * bstride + (size_t)c * 1024 + lane * 16;
  const uint4 u = *(const uint4*)p;
  const int w4[4] = {(int)u.x, (int)u.y, (int)u.z, (int)u.w};
  float s = 0.f, s2 = 0.f;
#pragma unroll
  for (int t = 0; t < 4; t++) {
    const v2f a = dec2<false>(w4[t]);
    const v2f bb = dec2<true>(w4[t]);
    s += (a[0] + a[1]) + (bb[0] + bb[1]);
    s2 += a[0] * a[0] + a[1] * a[1] + bb[0] * bb[0] + bb[1] * bb[1];
  }
#pragma unroll
  for (int off = 32; off > 0; off >>= 1) {
    s += __shfl_down(s, off, 64);
    s2 += __shfl_down(s2, off, 64);
  }
  __shared__ float rs[4], rq[4];
  const int w = tid >> 6;
  if (lane == 0) { rs[w] = s; rq[w] = s2; }
  __syncthreads();
  if (tid == 0) {
    float2 o = make_float2(rs[0] + rs[1] + rs[2] + rs[3],
                           rq[0] + rq[1] + rq[2] + rq[3]);
    *(float2*)(P + (size_t)(c * 8 + part) * 2) = o;
  }
}

// -------- fused BN(finalize)+apply+spike: q (transpose) and k/v, one dispatch -----
// blocks [0,16384): qT tiles; [16384,32768): k/v linear (8192 each).
__global__ __launch_bounds__(256) void apply_all_k(const uchar* __restrict__ qkv8,
                                                   uchar* __restrict__ q8,
                                                   uchar* __restrict__ k8,
                                                   uchar* __restrict__ v8,
                                                   const float* __restrict__ P,
                                                   const float* __restrict__ qg, const float* __restrict__ qb,
                                                   const float* __restrict__ kg, const float* __restrict__ kb,
                                                   const float* __restrict__ vg, const float* __restrict__ vb) {
  const int bid = blockIdx.x;
  const int tid = threadIdx.x;
  if (bid < 16384) {
    // q: BN-apply + spike + transpose -> q8 [B,N,C]
    __shared__ uchar tile[32][33];
    const int nb = bid & 31, cb = (bid >> 5) & 15, b = bid >> 9;
    const int n0 = nb * 32, c0 = cb * 32;
    const uchar* in = qkv8 + (size_t)b * (1536 * 1024);
    const int cl = tid >> 3;            // 0..31
    const int n4 = (tid & 7) * 4;       // 0..28
    const int c = c0 + cl;
    const float2 ab = chan_affine(P, c, qg[c], qb[c]);
    const unsigned w = *(const unsigned*)(in + (size_t)c * 1024 + n0 + n4);
    const v2f a = dec2<false>((int)w);
    const v2f bb = dec2<true>((int)w);
    tile[cl][n4 + 0] = (ab.x * a[0] + ab.y >= 1.1f) ? (uchar)0x38 : (uchar)0;
    tile[cl][n4 + 1] = (ab.x * a[1] + ab.y >= 1.1f) ? (uchar)0x38 : (uchar)0;
    tile[cl][n4 + 2] = (ab.x * bb[0] + ab.y >= 1.1f) ? (uchar)0x38 : (uchar)0;
    tile[cl][n4 + 3] = (ab.x * bb[1] + ab.y >= 1.1f) ? (uchar)0x38 : (uchar)0;
    __syncthreads();
    uchar* out = q8 + (size_t)b * (NN * CC);
    const int nl = tid >> 3;
    const int cq = (tid & 7) * 4;
    uchar4 v;
    v.x = tile[cq][nl]; v.y = tile[cq + 1][nl];
    v.z = tile[cq + 2][nl]; v.w = tile[cq + 3][nl];
    *(uchar4*)(out + (size_t)(n0 + nl) * CC + c0 + cq) = v;
  } else {
    // k/v: BN-apply + spike in [B,C,N]
    const int t0 = bid - 16384;
    const int sec = t0 >> 13;           // 0:k, 1:v
    const int blk = t0 & 8191;
    const size_t t = (size_t)blk * 256 + tid;
    const size_t i = t * 8;
    const int b = (int)(i >> 19);
    const int rem = (int)(i & 524287);
    const int c = rem >> 10, n = rem & 1023;
    const int cg = 512 + 512 * sec + c;
    const float2 ab = chan_affine(P, cg, sec ? vg[c] : kg[c], sec ? vb[c] : kb[c]);
    const uchar* src = qkv8 + (size_t)b * (1536 * 1024) + (size_t)cg * 1024 + n;
    const uint2 u = *(const uint2*)src;
    ull packed = 0;
    {
      const v2f a = dec2<false>((int)u.x);
      const v2f bb = dec2<true>((int)u.x);
      const float f[4] = {a[0], a[1], bb[0], bb[1]};
#pragma unroll
      for (int j = 0; j < 4; j++)
        packed |= ((ab.x * f[j] + ab.y >= 1.1f) ? 0x38ull : 0ull) << (8 * j);
    }
    {
      const v2f a = dec2<false>((int)u.y);
      const v2f bb = dec2<true>((int)u.y);
      const float f[4] = {a[0], a[1], bb[0], bb[1]};
#pragma unroll
      for (int j = 0; j < 4; j++)
        packed |= ((ab.x * f[j] + ab.y >= 1.1f) ? 0x38ull : 0ull) << (8 * (4 + j));
    }
    uchar* dst = (sec ? v8 : k8) + (size_t)b * (CC * NN) + (size_t)c * 1024 + n;
    *(ull*)dst = packed;
  }
}

// -------- final BN(finalize)+apply+spike -> fp32 output ---------------------------
__global__ __launch_bounds__(256) void apply_final_k(const uchar* __restrict__ in,
                                                     float* __restrict__ outp,
                                                     const float* __restrict__ Pp,
                                                     const float* __restrict__ pg,
                                                     const float* __restrict__ pb) {
  const size_t idx = ((size_t)blockIdx.x * 256 + threadIdx.x) * 8;
  const int c = (int)((idx >> 10) & (CC - 1));
  const float2 ab = chan_affine(Pp, c, pg[c], pb[c]);
  const uint2 u = *(const uint2*)(in + idx);
  float of[8];
  {
    const v2f a = dec2<false>((int)u.x);
    const v2f bb = dec2<true>((int)u.x);
    of[0] = (ab.x * a[0] + ab.y >= 1.1f) ? 1.f : 0.f;
    of[1] = (ab.x * a[1] + ab.y >= 1.1f) ? 1.f : 0.f;
    of[2] = (ab.x * bb[0] + ab.y >= 1.1f) ? 1.f : 0.f;
    of[3] = (ab.x * bb[1] + ab.y >= 1.1f) ? 1.f : 0.f;
  }
  {
    const v2f a = dec2<false>((int)u.y);
    const v2f bb = dec2<true>((int)u.y);
    of[4] = (ab.x * a[0] + ab.y >= 1.1f) ? 1.f : 0.f;
    of[5] = (ab.x * a[1] + ab.y >= 1.1f) ? 1.f : 0.f;
    of[6] = (ab.x * bb[0] + ab.y >= 1.1f) ? 1.f : 0.f;
    of[7] = (ab.x * bb[1] + ab.y >= 1.1f) ? 1.f : 0.f;
  }
  float* op = outp + idx;
  *(float4*)op = make_float4(of[0], of[1], of[2], of[3]);
  *(float4*)(op + 4) = make_float4(of[4], of[5], of[6], of[7]);
}

// -------- fused prep: x transpose->fp8 [blocks 0,16384) + weight cvt [16384,17408)
__global__ __launch_bounds__(256) void prep_k(const float* __restrict__ x,
                                              const float* __restrict__ w0, const float* __restrict__ w1,
                                              const float* __restrict__ w2, const float* __restrict__ w3,
                                              uchar* __restrict__ xT8,
                                              uchar* __restrict__ o0, uchar* __restrict__ o1,
                                              uchar* __restrict__ o2, uchar* __restrict__ o3) {
  const int bid = blockIdx.x;
  const int tid = threadIdx.x;
  if (bid < 16384) {
    __shared__ uchar tile[32][33];
    const int nb = bid & 31, cb = (bid >> 5) & 15, b = bid >> 9;
    const int n0 = nb * 32, c0 = cb * 32;
    const float* in = x + (size_t)b * (CC * NN);
    const int tx = tid & 31, ty = tid >> 5;
#pragma unroll
    for (int i = 0; i < 32; i += 8) {
      tile[ty + i][tx] = enc1(in[(size_t)(c0 + ty + i) * NN + n0 + tx]);
    }
    __syncthreads();
    uchar* o = xT8 + (size_t)b * (NN * CC);
    const int nl = tid >> 3;
    const int cq = (tid & 7) * 4;
    uchar4 v;
    v.x = tile[cq][nl]; v.y = tile[cq + 1][nl];
    v.z = tile[cq + 2][nl]; v.w = tile[cq + 3][nl];
    *(uchar4*)(o + (size_t)(n0 + nl) * CC + c0 + cq) = v;
  } else {
    const int t = bid - 16384;      // [0,1024)
    const int mat = t >> 8, blk = t & 255;
    const float* src = (mat == 0) ? w0 : (mat == 1) ? w1 : (mat == 2) ? w2 : w3;
    uchar* dst = (mat == 0) ? o0 : (mat == 1) ? o1 : (mat == 2) ? o2 : o3;
    const int i = (blk * 256 + tid) * 4;
    float4 v = *(const float4*)(src + i);
    *(unsigned*)(dst + i) = pk4_fp8(v.x, v.y, v.z, v.w);
  }
}

extern "C" void kernel_launch(void* const* d_in, const int* in_sizes, int n_in,
                              void* d_out, int out_size, void* d_ws, size_t ws_size,
                              hipStream_t stream) {
  const float* x          = (const float*)d_in[0];
  const float* q_w        = (const float*)d_in[1];
  const float* q_gamma    = (const float*)d_in[2];
  const float* q_beta     = (const float*)d_in[3];
  const float* k_w        = (const float*)d_in[4];
  const float* k_gamma    = (const float*)d_in[5];
  const float* k_beta     = (const float*)d_in[6];
  const float* v_w        = (const float*)d_in[7];
  const float* v_gamma    = (const float*)d_in[8];
  const float* v_beta     = (const float*)d_in[9];
  const float* proj_w     = (const float*)d_in[10];
  const float* proj_gamma = (const float*)d_in[11];
  const float* proj_beta  = (const float*)d_in[12];
  const float* proj_b     = (const float*)d_in[13];

  char* base = (char*)d_ws;
  const size_t MB = 1u << 20;
  uchar*  xT8    = (uchar*)base;                // 16 MB [B,N,C] fp8
  uchar*  qkv8   = (uchar*)(base + 16 * MB);    // 48 MB [B,1536,1024] fp8 pre-acts
  uchar*  q8     = (uchar*)(base + 64 * MB);    // 16 MB [B,N,C] fp8 spikes
  uchar*  k8     = (uchar*)(base + 80 * MB);    // 16 MB [B,C,N]
  uchar*  v8     = (uchar*)(base + 96 * MB);    // 16 MB [B,C,N]
  uchar*  kvT8   = (uchar*)(base + 112 * MB);   //  8 MB [B,d,c]
  uchar*  attnT8 = (uchar*)(base + 120 * MB);   // 16 MB [B,N,d]
  uchar*  outpre8= (uchar*)(base + 136 * MB);   // 16 MB [B,C,N] fp8 proj pre-acts
  uchar*  wqkv8  = (uchar*)(base + 152 * MB);   // stacked q|k|v fp8
  uchar*  wp8    = wqkv8 + 3 * CC * CC;
  float*  P      = (float*)(base + 154 * MB);   // conv partials [1536][8][2]
  float*  Pp     = P + 1536 * 16;               // proj partials [512][8][2]
  float* dout = (float*)d_out;

  const long QKVL = (long)3 * CC * NN;   // fp8 bytes per batch
  const long NCL  = (long)NN * CC;
  const long CNL  = (long)CC * NN;
  const long KVL  = (long)CC * CC;

  // fused prep: x -> xT8 fp8 + weights -> fp8
  prep_k<<<17408, 256, 0, stream>>>(x, q_w, k_w, v_w, proj_w, xT8,
                                    wqkv8, wqkv8 + CC * CC, wqkv8 + 2 * CC * CC, wp8);

  // merged q/k/v conv -> fp8 pre-acts (256^2 phased)
  gemm8p<2><<<dim3(NN / 256, 1536 / 256, BB), 512, 0, stream>>>(
      wqkv8, xT8, qkv8, nullptr, 1536, NN, CC, 0, NCL, QKVL);

  // BN stats from stored fp8
  stats_part8_k<<<dim3(8, 1536), 256, 0, stream>>>(qkv8, P, QKVL);

  // fused finalize+apply: q (transpose) + k + v spikes, one dispatch
  apply_all_k<<<32768, 256, 0, stream>>>(qkv8, q8, k8, v8, P,
                                         q_gamma, q_beta, k_gamma, k_beta,
                                         v_gamma, v_beta);

  // kvT8[d][c] = sum_n v[d][n] k[c][n]   (512x512 -> stays on 128^2 path)
  gemm8<0><<<dim3(CC / 128, CC / 128, BB), 256, 0, stream>>>(
      v8, k8, kvT8, nullptr, CC, CC, NN, CNL, CNL, KVL);
  // attnT8[n][d] = spike( sum_c q8[n][c]*kvT8[d][c] * 0.125, vth=0.5 ) (256^2 phased)
  gemm8p<1><<<dim3(CC / 256, NN / 256, BB), 512, 0, stream>>>(
      q8, kvT8, attnT8, nullptr, NN, CC, CC, NCL, KVL, NCL);
  // proj -> fp8 pre-acts (+bias) (256^2 phased)
  gemm8p<3><<<dim3(NN / 256, CC / 256, BB), 512, 0, stream>>>(
      wp8, attnT8, outpre8, proj_b, CC, NN, CC, 0, NCL, CNL);

  // final BN stats + fused finalize+apply -> fp32 out
  stats_part8_k<<<dim3(8, CC), 256, 0, stream>>>(outpre8, Pp, CNL);
  apply_final_k<<<8192, 256, 0, stream>>>(outpre8, dout, Pp, proj_gamma, proj_beta);
}

// Round 4
// 299.426 us; speedup vs baseline: 1.0758x; 1.0458x over previous
//
#include <hip/hip_runtime.h>
#include <cstddef>

// SSA forward, round 20:
//  - gemm8p v2: counted-vmcnt 2-tile-deep pipeline (T4). Prologue stages K-tiles
//    0 AND 1; per tile: s_waitcnt vmcnt(8) (never a mid-loop drain) + 1 barrier,
//    then the full 32-MFMA tile body with NO internal barriers (staging for t+2
//    is issued after the tail barrier into the just-freed buffer). Barriers/block
//    32 -> <=8. Waves de-lockstepped within a tile so ds_read and MFMA overlap
//    across waves on each SIMD. Accumulation order unchanged -> bit-identical.
//  - Round-19 post-mortem: 4-phase lockstep + per-tile vmcnt(0) drain gave only
//    17% MfmaUtil (m218's "phase-split with drain0 ~= no split" law).

#define CC 512
#define BB 32
#define NN 1024

typedef __attribute__((ext_vector_type(4))) float v4f;
typedef __attribute__((ext_vector_type(2))) float v2f;
typedef __attribute__((ext_vector_type(4))) int v4i;
typedef __attribute__((ext_vector_type(8))) int v8i;
typedef unsigned char uchar;
typedef unsigned long long ull;

// ---- soft fallbacks --------------------------------------------------------------
__device__ __forceinline__ uchar f2e4s(float v) {
  const uchar s = (v < 0.f) ? 0x80 : 0x00;
  float a = fabsf(v);
  if (a >= 464.f) return s | 0x7E;
  if (a < 0.015625f) {
    int q = (int)rintf(a * 512.f);
    return s | (uchar)q;
  }
  const int e = (int)((__float_as_uint(a) >> 23) & 0xFF) - 126;
  const float scale = __uint_as_float((unsigned)(4 - e + 127) << 23);
  const int q = (int)rintf(a * scale);
  int code = ((e - 1 + 7) << 3) + (q - 8);
  if (code > 0x7E) code = 0x7E;
  return s | (uchar)code;
}
__device__ __forceinline__ float e42f(uchar b) {
  const int e = (b >> 3) & 15, m = b & 7;
  const float mag = e ? __uint_as_float((unsigned)((e + 120) << 23) | ((unsigned)m << 20))
                      : (float)m * 0.001953125f;
  return (b & 0x80) ? -mag : mag;
}

// ---- HW converters (gfx950 OCP e4m3), guarded ------------------------------------
__device__ __forceinline__ unsigned pk4_fp8(float a0, float a1, float a2, float a3) {
#if __has_builtin(__builtin_amdgcn_cvt_pk_fp8_f32)
  int r = __builtin_amdgcn_cvt_pk_fp8_f32(a0, a1, 0, false);
  r = __builtin_amdgcn_cvt_pk_fp8_f32(a2, a3, r, true);
  return (unsigned)r;
#else
  return (unsigned)f2e4s(a0) | ((unsigned)f2e4s(a1) << 8) |
         ((unsigned)f2e4s(a2) << 16) | ((unsigned)f2e4s(a3) << 24);
#endif
}
__device__ __forceinline__ uchar enc1(float v) {
#if __has_builtin(__builtin_amdgcn_cvt_pk_fp8_f32)
  return (uchar)(__builtin_amdgcn_cvt_pk_fp8_f32(v, v, 0, false) & 0xFF);
#else
  return f2e4s(v);
#endif
}
template <bool HI>
__device__ __forceinline__ v2f dec2(int src) {
#if __has_builtin(__builtin_amdgcn_cvt_pk_f32_fp8)
  return __builtin_amdgcn_cvt_pk_f32_fp8(src, HI);
#else
  v2f r;
  const int s = HI ? (src >> 16) : src;
  r[0] = e42f((uchar)s);
  r[1] = e42f((uchar)(s >> 8));
  return r;
#endif
}

__device__ __forceinline__ void gload16(const void* g, void* l) {
  __builtin_amdgcn_global_load_lds(
      (const __attribute__((address_space(1))) unsigned int*)g,
      (__attribute__((address_space(3))) unsigned int*)l, 16, 0, 0);
}

// ---- channel affine from 8 partials (same fp order as the old finalize) ----------
__device__ __forceinline__ float2 chan_affine(const float* __restrict__ P, int c,
                                              float g, float bt) {
  const float* pc = P + (size_t)c * 16;
  float S = 0.f, Q = 0.f;
#pragma unroll
  for (int t = 0; t < 8; t++) { S += pc[2 * t]; Q += pc[2 * t + 1]; }
  const float mean = S * (1.f / 32768.f);
  const float var = fmaxf(Q * (1.f / 32768.f) - mean * mean, 0.f);
  const float rinv = 1.f / sqrtf(var + 1e-5f);
  const float a = g * rinv;
  return make_float2(a, bt - mean * a);
}

// ---------------- batched NT GEMM, MX fp8, 128x128 tile, BK=128 (legacy path) -----
// EPI: 0 = fp8 (kv ints); 1 = attn spike {0,0x38}; 2 = fp8 pre-act; 3 = +bias.
template <int EPI>
__global__ __launch_bounds__(256) void gemm8(const uchar* __restrict__ A,
                                             const uchar* __restrict__ B,
                                             uchar* __restrict__ Cout,
                                             const float* __restrict__ bias,
                                             int M, int N, int K,
                                             long sA, long sB, long sC) {
  __shared__ __align__(16) uchar lds[32768];  // A [0,16384), B [16384,32768)
  const int b = blockIdx.z;
  const uchar* Ab = A + (size_t)b * sA;
  const uchar* Bb = B + (size_t)b * sB;
  const int m0 = blockIdx.y * 128, n0 = blockIdx.x * 128;
  const int tid = threadIdx.x;
  const int wave = tid >> 6, lane = tid & 63;
  const int lrow = lane & 15, lquad = lane >> 4;
  const int wr = wave >> 1, wc = wave & 1;

  v4f acc[4][4];
#pragma unroll
  for (int i = 0; i < 4; i++)
#pragma unroll
    for (int j = 0; j < 4; j++) acc[i][j] = (v4f)0.f;

  const uchar* gA0 = Ab + (size_t)(m0 + 32 * wave + lrow) * K + lquad * 32;
  const uchar* gA1 = gA0 + (size_t)16 * K;
  const uchar* gB0 = Bb + (size_t)(n0 + 32 * wave + lrow) * K + lquad * 32;
  const uchar* gB1 = gB0 + (size_t)16 * K;
  uchar* lA0 = lds + (2 * wave) * 2048;
  uchar* lA1 = lA0 + 2048;
  uchar* lB0 = lds + 16384 + (2 * wave) * 2048;
  uchar* lB1 = lB0 + 2048;

  for (int k0 = 0; k0 < K; k0 += 128) {
    gload16(gA0, lA0);
    gload16(gA0 + 16, lA0 + 1024);
    gload16(gA1, lA1);
    gload16(gA1 + 16, lA1 + 1024);
    gload16(gB0, lB0);
    gload16(gB0 + 16, lB0 + 1024);
    gload16(gB1, lB1);
    gload16(gB1 + 16, lB1 + 1024);
    gA0 += 128; gA1 += 128; gB0 += 128; gB1 += 128;
    __syncthreads();
    const uchar* ra = lds + (size_t)(4 * wr) * 2048 + 16 * lane;
    const uchar* rb = lds + 16384 + (size_t)(4 * wc) * 2048 + 16 * lane;
    v8i af[4], bf[4];
#pragma unroll
    for (int i = 0; i < 4; i++) {
      const v4i lo = *(const v4i*)(ra + i * 2048);
      const v4i hi = *(const v4i*)(ra + i * 2048 + 1024);
      af[i][0] = lo[0]; af[i][1] = lo[1]; af[i][2] = lo[2]; af[i][3] = lo[3];
      af[i][4] = hi[0]; af[i][5] = hi[1]; af[i][6] = hi[2]; af[i][7] = hi[3];
    }
#pragma unroll
    for (int j = 0; j < 4; j++) {
      const v4i lo = *(const v4i*)(rb + j * 2048);
      const v4i hi = *(const v4i*)(rb + j * 2048 + 1024);
      bf[j][0] = lo[0]; bf[j][1] = lo[1]; bf[j][2] = lo[2]; bf[j][3] = lo[3];
      bf[j][4] = hi[0]; bf[j][5] = hi[1]; bf[j][6] = hi[2]; bf[j][7] = hi[3];
    }
#pragma unroll
    for (int i = 0; i < 4; i++)
#pragma unroll
      for (int j = 0; j < 4; j++)
        acc[i][j] = __builtin_amdgcn_mfma_scale_f32_16x16x128_f8f6f4(
            af[i], bf[j], acc[i][j], 0, 0, 0, 127, 0, 127);
    __syncthreads();
  }

  if (EPI == 3) {
#pragma unroll
    for (int mi = 0; mi < 4; mi++)
#pragma unroll
      for (int r = 0; r < 4; r++) {
        const float bi = bias[m0 + 64 * wr + 16 * mi + lquad * 4 + r];
#pragma unroll
        for (int ni = 0; ni < 4; ni++) acc[mi][ni][r] += bi;
      }
  }

  // Epilogue. C/D layout: col = lane&15, row = lquad*4 + reg.
#pragma unroll
  for (int mi = 0; mi < 4; mi++) {
    const int row0 = m0 + 64 * wr + 16 * mi + lquad * 4;
#pragma unroll
    for (int ni = 0; ni < 4; ni++) {
      const int col = n0 + 64 * wc + 16 * ni + lrow;
      uchar* cp = Cout + (size_t)b * sC + (size_t)row0 * N + col;
      if (EPI == 1) {
#pragma unroll
        for (int r = 0; r < 4; r++) {
          const float u = (acc[mi][ni][r] * 0.125f) / 1.1f - 0.5f;
          cp[(size_t)r * N] = (u >= 0.f) ? (uchar)0x38 : (uchar)0;
        }
      } else {
        const unsigned pk = pk4_fp8(acc[mi][ni][0], acc[mi][ni][1],
                                    acc[mi][ni][2], acc[mi][ni][3]);
#pragma unroll
        for (int r = 0; r < 4; r++) cp[(size_t)r * N] = (uchar)(pk >> (8 * r));
      }
    }
  }
}

// ---------------- phased batched NT GEMM, MX fp8, 256x256 tile, BK=128 ------------
// 8 waves (2M x 4N). LDS: 2 x 64KB double buffer. 2-tile-deep counted-vmcnt
// pipeline: prologue stages tiles 0+1; tile head waits vmcnt(8) (tile t done,
// t+1 in flight) + 1 barrier; tile body = 32 MFMA with NO internal barriers;
// tail barrier only when staging t+2 into the just-freed buffer.
template <int EPI>
__global__ __launch_bounds__(512, 2) void gemm8p(const uchar* __restrict__ A,
                                                 const uchar* __restrict__ B,
                                                 uchar* __restrict__ Cout,
                                                 const float* __restrict__ bias,
                                                 int M, int N, int K,
                                                 long sA, long sB, long sC) {
  __shared__ __align__(16) uchar lds[131072];
  const int b = blockIdx.z;
  const uchar* Ab = A + (size_t)b * sA;
  const uchar* Bb = B + (size_t)b * sB;
  const int m0 = blockIdx.y * 256, n0 = blockIdx.x * 256;
  const int tid = threadIdx.x;
  const int wave = tid >> 6, lane = tid & 63;
  const int lrow = lane & 15, lquad = lane >> 4;
  const int wr = wave >> 2, wc = wave & 3;

  v4f acc[8][4];
#pragma unroll
  for (int i = 0; i < 8; i++)
#pragma unroll
    for (int j = 0; j < 4; j++) acc[i][j] = (v4f)0.f;

  // staging: wave w covers A rows m0+32w..+31 and B rows n0+32w..+31
  const uchar* gA0 = Ab + (size_t)(m0 + 32 * wave + lrow) * K + lquad * 32;
  const uchar* gA1 = gA0 + (size_t)16 * K;
  const uchar* gB0 = Bb + (size_t)(n0 + 32 * wave + lrow) * K + lquad * 32;
  const uchar* gB1 = gB0 + (size_t)16 * K;

  const int NT = K >> 7;

  // stage current gA/gB K-chunk into buffer bufi, then advance pointers. 8 loads.
  auto stage = [&](int bufi) {
    uchar* la = lds + bufi * 65536 + (2 * wave) * 2048;
    uchar* lb = la + 32768;
    gload16(gA0, la);
    gload16(gA0 + 16, la + 1024);
    gload16(gA1, la + 2048);
    gload16(gA1 + 16, la + 3072);
    gload16(gB0, lb);
    gload16(gB0 + 16, lb + 1024);
    gload16(gB1, lb + 2048);
    gload16(gB1 + 16, lb + 3072);
    gA0 += 128; gA1 += 128; gB0 += 128; gB1 += 128;
  };

  // prologue: 2-deep
  stage(0);
  if (NT > 1) stage(1);

  for (int kt = 0; kt < NT; ++kt) {
    const int cur = kt & 1;
    // counted wait: outstanding <= tile t's 8 + tile t+1's 8; <=8 ==> tile t done.
    if (kt + 1 < NT) {
      asm volatile("s_waitcnt vmcnt(8)" ::: "memory");
    } else {
      asm volatile("s_waitcnt vmcnt(0)" ::: "memory");
    }
    __builtin_amdgcn_s_barrier();  // all waves' tile-t loads visible

    const uchar* raA = lds + cur * 65536 + (size_t)(8 * wr) * 2048 + 16 * lane;
    const uchar* raB = lds + cur * 65536 + 32768 + (size_t)(4 * wc) * 2048 + 16 * lane;
    v8i bf[4];
#pragma unroll
    for (int j = 0; j < 4; ++j) {
      const v4i lo = *(const v4i*)(raB + j * 2048);
      const v4i hi = *(const v4i*)(raB + j * 2048 + 1024);
      bf[j][0] = lo[0]; bf[j][1] = lo[1]; bf[j][2] = lo[2]; bf[j][3] = lo[3];
      bf[j][4] = hi[0]; bf[j][5] = hi[1]; bf[j][6] = hi[2]; bf[j][7] = hi[3];
    }
#pragma unroll
    for (int p = 0; p < 4; ++p) {
      const uchar* ra = raA + (size_t)(2 * p) * 2048;
      const v4i a0lo = *(const v4i*)(ra);
      const v4i a0hi = *(const v4i*)(ra + 1024);
      const v4i a1lo = *(const v4i*)(ra + 2048);
      const v4i a1hi = *(const v4i*)(ra + 3072);
      v8i af0, af1;
      af0[0] = a0lo[0]; af0[1] = a0lo[1]; af0[2] = a0lo[2]; af0[3] = a0lo[3];
      af0[4] = a0hi[0]; af0[5] = a0hi[1]; af0[6] = a0hi[2]; af0[7] = a0hi[3];
      af1[0] = a1lo[0]; af1[1] = a1lo[1]; af1[2] = a1lo[2]; af1[3] = a1lo[3];
      af1[4] = a1hi[0]; af1[5] = a1hi[1]; af1[6] = a1hi[2]; af1[7] = a1hi[3];
      __builtin_amdgcn_s_setprio(1);
#pragma unroll
      for (int j = 0; j < 4; ++j) {
        acc[2 * p][j] = __builtin_amdgcn_mfma_scale_f32_16x16x128_f8f6f4(
            af0, bf[j], acc[2 * p][j], 0, 0, 0, 127, 0, 127);
        acc[2 * p + 1][j] = __builtin_amdgcn_mfma_scale_f32_16x16x128_f8f6f4(
            af1, bf[j], acc[2 * p + 1][j], 0, 0, 0, 127, 0, 127);
      }
      __builtin_amdgcn_s_setprio(0);
    }

    if (kt + 2 < NT) {
      __builtin_amdgcn_s_barrier();  // all waves done reading buf[cur]
      stage(cur);                    // tile t+2 -> just-freed buffer
    }
  }

  if (EPI == 3) {
#pragma unroll
    for (int mi = 0; mi < 8; mi++)
#pragma unroll
      for (int r = 0; r < 4; r++) {
        const float bi = bias[m0 + 128 * wr + 16 * mi + lquad * 4 + r];
#pragma unroll
        for (int ni = 0; ni < 4; ni++) acc[mi][ni][r] += bi;
      }
  }

  // Epilogue. C/D layout: col = lane&15, row = lquad*4 + reg.
#pragma unroll
  for (int mi = 0; mi < 8; mi++) {
    const int row0 = m0 + 128 * wr + 16 * mi + lquad * 4;
#pragma unroll
    for (int ni = 0; ni < 4; ni++) {
      const int col = n0 + 64 * wc + 16 * ni + lrow;
      uchar* cp = Cout + (size_t)b * sC + (size_t)row0 * N + col;
      if (EPI == 1) {
#pragma unroll
        for (int r = 0; r < 4; r++) {
          const float u = (acc[mi][ni][r] * 0.125f) / 1.1f - 0.5f;
          cp[(size_t)r * N] = (u >= 0.f) ? (uchar)0x38 : (uchar)0;
        }
      } else {
        const unsigned pk = pk4_fp8(acc[mi][ni][0], acc[mi][ni][1],
                                    acc[mi][ni][2], acc[mi][ni][3]);
#pragma unroll
        for (int r = 0; r < 4; r++) cp[(size_t)r * N] = (uchar)(pk >> (8 * r));
      }
    }
  }
}

// -------- BN partial stats from stored fp8: grid (8, nch) -------------------------
__global__ __launch_bounds__(256) void stats_part8_k(const uchar* __restrict__ in,
                                                     float* __restrict__ P,
                                                     long bstride) {
  const int part = blockIdx.x, c = blockIdx.y;
  const int tid = threadIdx.x;
  const int bi = part * 4 + (tid >> 6);
  const int lane = tid & 63;
  const uchar* p = in + (size_t)bi * bstride + (size_t)c * 1024 + lane * 16;
  const uint4 u = *(const uint4*)p;
  const int w4[4] = {(int)u.x, (int)u.y, (int)u.z, (int)u.w};
  float s = 0.f, s2 = 0.f;
#pragma unroll
  for (int t = 0; t < 4; t++) {
    const v2f a = dec2<false>(w4[t]);
    const v2f bb = dec2<true>(w4[t]);
    s += (a[0] + a[1]) + (bb[0] + bb[1]);
    s2 += a[0] * a[0] + a[1] * a[1] + bb[0] * bb[0] + bb[1] * bb[1];
  }
#pragma unroll
  for (int off = 32; off > 0; off >>= 1) {
    s += __shfl_down(s, off, 64);
    s2 += __shfl_down(s2, off, 64);
  }
  __shared__ float rs[4], rq[4];
  const int w = tid >> 6;
  if (lane == 0) { rs[w] = s; rq[w] = s2; }
  __syncthreads();
  if (tid == 0) {
    float2 o = make_float2(rs[0] + rs[1] + rs[2] + rs[3],
                           rq[0] + rq[1] + rq[2] + rq[3]);
    *(float2*)(P + (size_t)(c * 8 + part) * 2) = o;
  }
}

// -------- fused BN(finalize)+apply+spike: q (transpose) and k/v, one dispatch -----
// blocks [0,16384): qT tiles; [16384,32768): k/v linear (8192 each).
__global__ __launch_bounds__(256) void apply_all_k(const uchar* __restrict__ qkv8,
                                                   uchar* __restrict__ q8,
                                                   uchar* __restrict__ k8,
                                                   uchar* __restrict__ v8,
                                                   const float* __restrict__ P,
                                                   const float* __restrict__ qg, const float* __restrict__ qb,
                                                   const float* __restrict__ kg, const float* __restrict__ kb,
                                                   const float* __restrict__ vg, const float* __restrict__ vb) {
  const int bid = blockIdx.x;
  const int tid = threadIdx.x;
  if (bid < 16384) {
    // q: BN-apply + spike + transpose -> q8 [B,N,C]
    __shared__ uchar tile[32][33];
    const int nb = bid & 31, cb = (bid >> 5) & 15, b = bid >> 9;
    const int n0 = nb * 32, c0 = cb * 32;
    const uchar* in = qkv8 + (size_t)b * (1536 * 1024);
    const int cl = tid >> 3;            // 0..31
    const int n4 = (tid & 7) * 4;       // 0..28
    const int c = c0 + cl;
    const float2 ab = chan_affine(P, c, qg[c], qb[c]);
    const unsigned w = *(const unsigned*)(in + (size_t)c * 1024 + n0 + n4);
    const v2f a = dec2<false>((int)w);
    const v2f bb = dec2<true>((int)w);
    tile[cl][n4 + 0] = (ab.x * a[0] + ab.y >= 1.1f) ? (uchar)0x38 : (uchar)0;
    tile[cl][n4 + 1] = (ab.x * a[1] + ab.y >= 1.1f) ? (uchar)0x38 : (uchar)0;
    tile[cl][n4 + 2] = (ab.x * bb[0] + ab.y >= 1.1f) ? (uchar)0x38 : (uchar)0;
    tile[cl][n4 + 3] = (ab.x * bb[1] + ab.y >= 1.1f) ? (uchar)0x38 : (uchar)0;
    __syncthreads();
    uchar* out = q8 + (size_t)b * (NN * CC);
    const int nl = tid >> 3;
    const int cq = (tid & 7) * 4;
    uchar4 v;
    v.x = tile[cq][nl]; v.y = tile[cq + 1][nl];
    v.z = tile[cq + 2][nl]; v.w = tile[cq + 3][nl];
    *(uchar4*)(out + (size_t)(n0 + nl) * CC + c0 + cq) = v;
  } else {
    // k/v: BN-apply + spike in [B,C,N]
    const int t0 = bid - 16384;
    const int sec = t0 >> 13;           // 0:k, 1:v
    const int blk = t0 & 8191;
    const size_t t = (size_t)blk * 256 + tid;
    const size_t i = t * 8;
    const int b = (int)(i >> 19);
    const int rem = (int)(i & 524287);
    const int c = rem >> 10, n = rem & 1023;
    const int cg = 512 + 512 * sec + c;
    const float2 ab = chan_affine(P, cg, sec ? vg[c] : kg[c], sec ? vb[c] : kb[c]);
    const uchar* src = qkv8 + (size_t)b * (1536 * 1024) + (size_t)cg * 1024 + n;
    const uint2 u = *(const uint2*)src;
    ull packed = 0;
    {
      const v2f a = dec2<false>((int)u.x);
      const v2f bb = dec2<true>((int)u.x);
      const float f[4] = {a[0], a[1], bb[0], bb[1]};
#pragma unroll
      for (int j = 0; j < 4; j++)
        packed |= ((ab.x * f[j] + ab.y >= 1.1f) ? 0x38ull : 0ull) << (8 * j);
    }
    {
      const v2f a = dec2<false>((int)u.y);
      const v2f bb = dec2<true>((int)u.y);
      const float f[4] = {a[0], a[1], bb[0], bb[1]};
#pragma unroll
      for (int j = 0; j < 4; j++)
        packed |= ((ab.x * f[j] + ab.y >= 1.1f) ? 0x38ull : 0ull) << (8 * (4 + j));
    }
    uchar* dst = (sec ? v8 : k8) + (size_t)b * (CC * NN) + (size_t)c * 1024 + n;
    *(ull*)dst = packed;
  }
}

// -------- final BN(finalize)+apply+spike -> fp32 output ---------------------------
__global__ __launch_bounds__(256) void apply_final_k(const uchar* __restrict__ in,
                                                     float* __restrict__ outp,
                                                     const float* __restrict__ Pp,
                                                     const float* __restrict__ pg,
                                                     const float* __restrict__ pb) {
  const size_t idx = ((size_t)blockIdx.x * 256 + threadIdx.x) * 8;
  const int c = (int)((idx >> 10) & (CC - 1));
  const float2 ab = chan_affine(Pp, c, pg[c], pb[c]);
  const uint2 u = *(const uint2*)(in + idx);
  float of[8];
  {
    const v2f a = dec2<false>((int)u.x);
    const v2f bb = dec2<true>((int)u.x);
    of[0] = (ab.x * a[0] + ab.y >= 1.1f) ? 1.f : 0.f;
    of[1] = (ab.x * a[1] + ab.y >= 1.1f) ? 1.f : 0.f;
    of[2] = (ab.x * bb[0] + ab.y >= 1.1f) ? 1.f : 0.f;
    of[3] = (ab.x * bb[1] + ab.y >= 1.1f) ? 1.f : 0.f;
  }
  {
    const v2f a = dec2<false>((int)u.y);
    const v2f bb = dec2<true>((int)u.y);
    of[4] = (ab.x * a[0] + ab.y >= 1.1f) ? 1.f : 0.f;
    of[5] = (ab.x * a[1] + ab.y >= 1.1f) ? 1.f : 0.f;
    of[6] = (ab.x * bb[0] + ab.y >= 1.1f) ? 1.f : 0.f;
    of[7] = (ab.x * bb[1] + ab.y >= 1.1f) ? 1.f : 0.f;
  }
  float* op = outp + idx;
  *(float4*)op = make_float4(of[0], of[1], of[2], of[3]);
  *(float4*)(op + 4) = make_float4(of[4], of[5], of[6], of[7]);
}

// -------- fused prep: x transpose->fp8 [blocks 0,16384) + weight cvt [16384,17408)
__global__ __launch_bounds__(256) void prep_k(const float* __restrict__ x,
                                              const float* __restrict__ w0, const float* __restrict__ w1,
                                              const float* __restrict__ w2, const float* __restrict__ w3,
                                              uchar* __restrict__ xT8,
                                              uchar* __restrict__ o0, uchar* __restrict__ o1,
                                              uchar* __restrict__ o2, uchar* __restrict__ o3) {
  const int bid = blockIdx.x;
  const int tid = threadIdx.x;
  if (bid < 16384) {
    __shared__ uchar tile[32][33];
    const int nb = bid & 31, cb = (bid >> 5) & 15, b = bid >> 9;
    const int n0 = nb * 32, c0 = cb * 32;
    const float* in = x + (size_t)b * (CC * NN);
    const int tx = tid & 31, ty = tid >> 5;
#pragma unroll
    for (int i = 0; i < 32; i += 8) {
      tile[ty + i][tx] = enc1(in[(size_t)(c0 + ty + i) * NN + n0 + tx]);
    }
    __syncthreads();
    uchar* o = xT8 + (size_t)b * (NN * CC);
    const int nl = tid >> 3;
    const int cq = (tid & 7) * 4;
    uchar4 v;
    v.x = tile[cq][nl]; v.y = tile[cq + 1][nl];
    v.z = tile[cq + 2][nl]; v.w = tile[cq + 3][nl];
    *(uchar4*)(o + (size_t)(n0 + nl) * CC + c0 + cq) = v;
  } else {
    const int t = bid - 16384;      // [0,1024)
    const int mat = t >> 8, blk = t & 255;
    const float* src = (mat == 0) ? w0 : (mat == 1) ? w1 : (mat == 2) ? w2 : w3;
    uchar* dst = (mat == 0) ? o0 : (mat == 1) ? o1 : (mat == 2) ? o2 : o3;
    const int i = (blk * 256 + tid) * 4;
    float4 v = *(const float4*)(src + i);
    *(unsigned*)(dst + i) = pk4_fp8(v.x, v.y, v.z, v.w);
  }
}

extern "C" void kernel_launch(void* const* d_in, const int* in_sizes, int n_in,
                              void* d_out, int out_size, void* d_ws, size_t ws_size,
                              hipStream_t stream) {
  const float* x          = (const float*)d_in[0];
  const float* q_w        = (const float*)d_in[1];
  const float* q_gamma    = (const float*)d_in[2];
  const float* q_beta     = (const float*)d_in[3];
  const float* k_w        = (const float*)d_in[4];
  const float* k_gamma    = (const float*)d_in[5];
  const float* k_beta     = (const float*)d_in[6];
  const float* v_w        = (const float*)d_in[7];
  const float* v_gamma    = (const float*)d_in[8];
  const float* v_beta     = (const float*)d_in[9];
  const float* proj_w     = (const float*)d_in[10];
  const float* proj_gamma = (const float*)d_in[11];
  const float* proj_beta  = (const float*)d_in[12];
  const float* proj_b     = (const float*)d_in[13];

  char* base = (char*)d_ws;
  const size_t MB = 1u << 20;
  uchar*  xT8    = (uchar*)base;                // 16 MB [B,N,C] fp8
  uchar*  qkv8   = (uchar*)(base + 16 * MB);    // 48 MB [B,1536,1024] fp8 pre-acts
  uchar*  q8     = (uchar*)(base + 64 * MB);    // 16 MB [B,N,C] fp8 spikes
  uchar*  k8     = (uchar*)(base + 80 * MB);    // 16 MB [B,C,N]
  uchar*  v8     = (uchar*)(base + 96 * MB);    // 16 MB [B,C,N]
  uchar*  kvT8   = (uchar*)(base + 112 * MB);   //  8 MB [B,d,c]
  uchar*  attnT8 = (uchar*)(base + 120 * MB);   // 16 MB [B,N,d]
  uchar*  outpre8= (uchar*)(base + 136 * MB);   // 16 MB [B,C,N] fp8 proj pre-acts
  uchar*  wqkv8  = (uchar*)(base + 152 * MB);   // stacked q|k|v fp8
  uchar*  wp8    = wqkv8 + 3 * CC * CC;
  float*  P      = (float*)(base + 154 * MB);   // conv partials [1536][8][2]
  float*  Pp     = P + 1536 * 16;               // proj partials [512][8][2]
  float* dout = (float*)d_out;

  const long QKVL = (long)3 * CC * NN;   // fp8 bytes per batch
  const long NCL  = (long)NN * CC;
  const long CNL  = (long)CC * NN;
  const long KVL  = (long)CC * CC;

  // fused prep: x -> xT8 fp8 + weights -> fp8
  prep_k<<<17408, 256, 0, stream>>>(x, q_w, k_w, v_w, proj_w, xT8,
                                    wqkv8, wqkv8 + CC * CC, wqkv8 + 2 * CC * CC, wp8);

  // merged q/k/v conv -> fp8 pre-acts (256^2 counted-vmcnt pipeline)
  gemm8p<2><<<dim3(NN / 256, 1536 / 256, BB), 512, 0, stream>>>(
      wqkv8, xT8, qkv8, nullptr, 1536, NN, CC, 0, NCL, QKVL);

  // BN stats from stored fp8
  stats_part8_k<<<dim3(8, 1536), 256, 0, stream>>>(qkv8, P, QKVL);

  // fused finalize+apply: q (transpose) + k + v spikes, one dispatch
  apply_all_k<<<32768, 256, 0, stream>>>(qkv8, q8, k8, v8, P,
                                         q_gamma, q_beta, k_gamma, k_beta,
                                         v_gamma, v_beta);

  // kvT8[d][c] = sum_n v[d][n] k[c][n]   (512x512 -> stays on 128^2 path)
  gemm8<0><<<dim3(CC / 128, CC / 128, BB), 256, 0, stream>>>(
      v8, k8, kvT8, nullptr, CC, CC, NN, CNL, CNL, KVL);
  // attnT8[n][d] = spike( sum_c q8[n][c]*kvT8[d][c] * 0.125, vth=0.5 )
  gemm8p<1><<<dim3(CC / 256, NN / 256, BB), 512, 0, stream>>>(
      q8, kvT8, attnT8, nullptr, NN, CC, CC, NCL, KVL, NCL);
  // proj -> fp8 pre-acts (+bias)
  gemm8p<3><<<dim3(NN / 256, CC / 256, BB), 512, 0, stream>>>(
      wp8, attnT8, outpre8, proj_b, CC, NN, CC, 0, NCL, CNL);

  // final BN stats + fused finalize+apply -> fp32 out
  stats_part8_k<<<dim3(8, CC), 256, 0, stream>>>(outpre8, Pp, CNL);
  apply_final_k<<<8192, 256, 0, stream>>>(outpre8, dout, Pp, proj_gamma, proj_beta);
}